// Round 7
// baseline (159.026 us; speedup 1.0000x reference)
//
#include <hip/hip_runtime.h>
#include <math.h>

// SSIM fused kernel for MI355X (gfx950), v7.
// A,B: [16,3,512,512] f32 -> scalar f32 mean(ssim_map).
// Separable 11-tap Gaussian, zero-padded SAME conv, 4 staged planes
// {hA, hB, h(A^2+B^2), h(AB)} (sigma1+sigma2 via linearity).
// v7 = v6 with:
//  - weights computed on HOST in f64 (matches NumPy's f64 exp/normalize),
//    passed as by-value kernel arg -> SGPRs. Kills ~150 VALU instrs/thread
//    (6 expf + 6 div per thread in v6; VALUBusy was stuck at 56%).
//  - plane-packed LDS [row][64][4], row stride 260 floats: h-pass stores
//    11 ds_write_b128 (was 44 b32), v-pass reads 18 ds_read_b128 (was 72
//    b32). Wave = one row in v-pass -> canonical conflict-free sweep.

#define IMG 512
#define C1F 1.0e-4f
#define C2F 9.0e-4f

#define SR  42               // h-rows per tile (TY=32 + 10 halo)
#define RSF 260              // row stride in floats: 64*4 planes + 4 pad (=4 mod 32)

#define NBLK 6144            // 8 * 16 * 48

struct GW { float g[11]; };

__global__ void ssim_finalize(const double* __restrict__ part, float* __restrict__ out) {
    const int t = threadIdx.x;           // 256 threads
    double v = 0.0;
    #pragma unroll
    for (int i = 0; i < NBLK / 256; ++i)     // 24 iters
        v += part[t + 256 * i];
    #pragma unroll
    for (int off = 32; off > 0; off >>= 1)
        v += __shfl_down(v, off, 64);
    __shared__ double w[4];
    if ((t & 63) == 0) w[t >> 6] = v;
    __syncthreads();
    if (t == 0)
        *out = (float)((w[0] + w[1] + w[2] + w[3]) / 12582912.0);  // 16*3*512^2
}

__global__ __launch_bounds__(256, 3)
void ssim_main(const float* __restrict__ A, const float* __restrict__ B,
               double* __restrict__ part, const GW gw)
{
    __shared__ float hbuf[SR * RSF];   // 10,920 floats = 43,680 B

    const int t  = threadIdx.x;
    const int x0 = blockIdx.x * 64;
    const int y0 = blockIdx.y * 32;
    const size_t pbase = (size_t)blockIdx.z * (size_t)(IMG * IMG);
    const float* __restrict__ pa = A + pbase;
    const float* __restrict__ pb = B + pbase;

    // ---------------- horizontal pass ----------------
    // 252 threads: r = t/6 (0..41), s = t%6. Segment s covers 11 output cols
    // starting at {0,11,22,33,44,53} (segs 4,5 overlap at cols 53,54: same
    // bit-identical value double-written, benign). Window: [start-5, start+15].
    if (t < 252) {
        const int r = t / 6;
        const int s = t - 6 * r;
        const int start = (s == 5) ? 53 : s * 11;
        const int gy  = y0 - 5 + r;
        const int gx0 = x0 + start - 5;
        const bool rowok = ((unsigned)gy < (unsigned)IMG);
        const float* __restrict__ ra = pa + (ptrdiff_t)gy * IMG;
        const float* __restrict__ rb = pb + (ptrdiff_t)gy * IMG;

        float wa[21], wb[21];
        if (rowok && gx0 >= 0 && gx0 + 20 < IMG) {
            #pragma unroll
            for (int j = 0; j < 21; ++j) {       // imm-offset scalar loads
                wa[j] = ra[gx0 + j];
                wb[j] = rb[gx0 + j];
            }
        } else {
            #pragma unroll
            for (int j = 0; j < 21; ++j) {
                const int gx = gx0 + j;
                const bool ok = rowok && ((unsigned)gx < (unsigned)IMG);
                wa[j] = ok ? ra[gx] : 0.f;
                wb[j] = ok ? rb[gx] : 0.f;
            }
        }

        // products-once scatter: 121 (m,p) pairs x 4 FMA, weights from SGPRs
        float sa[11], sb[11], ss[11], sp[11];
        #pragma unroll
        for (int p = 0; p < 11; ++p)
        { sa[p]=0.f; sb[p]=0.f; ss[p]=0.f; sp[p]=0.f; }
        #pragma unroll
        for (int m = 0; m < 21; ++m) {
            const float a = wa[m];
            const float b = wb[m];
            const float s2v = a * a + b * b;     // A^2 + B^2 (conv is linear)
            const float ab  = a * b;
            #pragma unroll
            for (int p = 0; p < 11; ++p) {
                const int k = m - p;             // tap index (compile-time)
                if (k >= 0 && k <= 10) {
                    const float w = gw.g[k];
                    sa[p] += w * a;   sb[p] += w * b;
                    ss[p] += w * s2v; sp[p] += w * ab;
                }
            }
        }

        const int base = r * RSF;
        #pragma unroll
        for (int p = 0; p < 11; ++p) {
            *(float4*)&hbuf[base + (start + p) * 4] =
                make_float4(sa[p], sb[p], ss[p], sp[p]);
        }
    }
    __syncthreads();

    // ---------------- vertical pass + SSIM ----------------
    // 256 threads: column x = t&63, output rows yb..yb+7 (yb = (t>>6)*8).
    // Wave = one h-row sweep: lanes read contiguous 1024B -> conflict-free.
    float lsum = 0.f;
    {
        const int x  = t & 63;
        const int yb = (t >> 6) << 3;
        float m1[8], m2[8], es[8], ep[8];
        #pragma unroll
        for (int j = 0; j < 8; ++j)
        { m1[j]=0.f; m2[j]=0.f; es[j]=0.f; ep[j]=0.f; }

        #pragma unroll
        for (int k = 0; k < 18; ++k) {
            const float4 q = *(const float4*)&hbuf[(yb + k) * RSF + x * 4];
            #pragma unroll
            for (int j = 0; j < 8; ++j) {
                const int kk = k - j;
                if (kk >= 0 && kk <= 10) {
                    const float w = gw.g[kk];
                    m1[j] += w * q.x; m2[j] += w * q.y;
                    es[j] += w * q.z; ep[j] += w * q.w;
                }
            }
        }

        #pragma unroll
        for (int j = 0; j < 8; ++j) {
            const float mu1 = m1[j], mu2 = m2[j];
            const float mu1s = mu1 * mu1, mu2s = mu2 * mu2, mu12 = mu1 * mu2;
            const float s12  = ep[j] - mu12;                 // sigma12
            const float ssum = es[j] - mu1s - mu2s;          // sigma1+sigma2
            const float num = (2.f * mu12 + C1F) * (2.f * s12 + C2F);
            const float den = (mu1s + mu2s + C1F) * (ssum + C2F);
            float rd = __builtin_amdgcn_rcpf(den);
            rd = rd * (2.f - den * rd);          // one NR step
            lsum += num * rd;
        }
    }

    // ---------------- reduction ----------------
    #pragma unroll
    for (int off = 32; off > 0; off >>= 1)
        lsum += __shfl_down(lsum, off, 64);

    __syncthreads();                  // LDS reads done; reuse hbuf for partials
    if ((t & 63) == 0) hbuf[t >> 6] = lsum;
    __syncthreads();
    if (t == 0) {
        const double bs = (double)hbuf[0] + (double)hbuf[1]
                        + (double)hbuf[2] + (double)hbuf[3];
        const int slot = blockIdx.x + (blockIdx.y << 3) + (blockIdx.z << 7);
        part[slot] = bs;              // private slot, no atomics
    }
}

extern "C" void kernel_launch(void* const* d_in, const int* in_sizes, int n_in,
                              void* d_out, int out_size, void* d_ws, size_t ws_size,
                              hipStream_t stream) {
    const float* A = (const float*)d_in[0];
    const float* B = (const float*)d_in[1];
    float* out   = (float*)d_out;
    double* part = (double*)d_ws;                // 6144 doubles = 48KB

    // Weights in f64, exactly the NumPy pipeline: exp(f64) -> sum(f64) ->
    // divide(f64) -> round to f32. Same every call (graph-capture safe).
    GW gw;
    {
        double e[11], s = 0.0;
        for (int i = 0; i < 11; ++i) {
            const double d = (double)(i - 5);
            e[i] = exp(-d * d / 4.5);
            s += e[i];
        }
        for (int i = 0; i < 11; ++i) gw.g[i] = (float)(e[i] / s);
    }

    dim3 grid(IMG / 64, IMG / 32, 48);           // (8, 16, 48) = 6144 blocks
    ssim_main<<<grid, dim3(256), 0, stream>>>(A, B, part, gw);
    ssim_finalize<<<dim3(1), dim3(256), 0, stream>>>(part, out);
}

// Round 8
// 154.436 us; speedup vs baseline: 1.0297x; 1.0297x over previous
//
#include <hip/hip_runtime.h>
#include <math.h>

// SSIM fused kernel for MI355X (gfx950), v8.
// A,B: [16,3,512,512] f32 -> scalar f32 mean(ssim_map).
// Separable 11-tap Gaussian, zero-padded SAME conv, 4 staged planes
// {hA, hB, h(A^2+B^2), h(AB)} (sigma1+sigma2 via linearity).
// v8 = v7 with load-batching to break serial load->wait->FMA chains
// (v7 showed VGPR=68: compiler sank loads into compute, serializing):
//  - h-pass: width-12 segments, starts {0,12,24,36,48,52} => window base
//    uniformly 4-aligned => 7 float4 loads x2 images (was 42 scalar),
//    loaded into explicit arrays BEFORE compute.
//  - v-pass: all 18 float4 LDS reads prefetched into q[18] before FMAs.
//  - raw v_rcp_f32 (no NR step); ~1ulp, slack is 2.6e-4 with absmax 0.0.

#define IMG 512
#define C1F 1.0e-4f
#define C2F 9.0e-4f

#define SR  42               // h-rows per tile (TY=32 + 10 halo)
#define RSF 260              // row stride in floats: 64*4 planes + 4 pad

#define NBLK 6144            // 8 * 16 * 48

struct GW { float g[11]; };

__global__ void ssim_finalize(const double* __restrict__ part, float* __restrict__ out) {
    const int t = threadIdx.x;           // 256 threads
    double v = 0.0;
    #pragma unroll
    for (int i = 0; i < NBLK / 256; ++i)     // 24 iters
        v += part[t + 256 * i];
    #pragma unroll
    for (int off = 32; off > 0; off >>= 1)
        v += __shfl_down(v, off, 64);
    __shared__ double w[4];
    if ((t & 63) == 0) w[t >> 6] = v;
    __syncthreads();
    if (t == 0)
        *out = (float)((w[0] + w[1] + w[2] + w[3]) / 12582912.0);  // 16*3*512^2
}

__global__ __launch_bounds__(256, 3)
void ssim_main(const float* __restrict__ A, const float* __restrict__ B,
               double* __restrict__ part, const GW gw)
{
    __shared__ float hbuf[SR * RSF];   // 10,920 floats = 43,680 B

    const int t  = threadIdx.x;
    const int x0 = blockIdx.x * 64;
    const int y0 = blockIdx.y * 32;
    const size_t pbase = (size_t)blockIdx.z * (size_t)(IMG * IMG);
    const float* __restrict__ pa = A + pbase;
    const float* __restrict__ pb = B + pbase;

    // ---------------- horizontal pass ----------------
    // 252 threads: r = t/6 (0..41), s = t%6. Segment s covers 12 output cols
    // from start in {0,12,24,36,48,52} (segs 4,5 overlap cols 52..59 with
    // bit-identical double-writes, benign). Window cols [start-8, start+20):
    // base is 4-aligned for ALL lanes -> 7 aligned float4 loads per image.
    // Taps use w[3+m], m=0..21 (cols start-5 .. start+16).
    if (t < 252) {
        const int r = t / 6;
        const int s = t - 6 * r;
        const int start = (s == 5) ? 52 : s * 12;
        const int gy  = y0 - 5 + r;
        const int gxb = x0 + start - 8;          // = 0 mod 4 always
        const bool rowok = ((unsigned)gy < (unsigned)IMG);
        const float* __restrict__ ra = pa + (ptrdiff_t)gy * IMG;
        const float* __restrict__ rb = pb + (ptrdiff_t)gy * IMG;

        float wa[28], wb[28];
        if (rowok && gxb >= 0 && gxb + 28 <= IMG) {
            const float4* va = (const float4*)(ra + gxb);
            const float4* vb = (const float4*)(rb + gxb);
            float4 qa[7], qb[7];
            #pragma unroll
            for (int q = 0; q < 7; ++q) qa[q] = va[q];   // batched: one wait
            #pragma unroll
            for (int q = 0; q < 7; ++q) qb[q] = vb[q];
            #pragma unroll
            for (int q = 0; q < 7; ++q) {
                wa[4*q+0] = qa[q].x; wa[4*q+1] = qa[q].y;
                wa[4*q+2] = qa[q].z; wa[4*q+3] = qa[q].w;
                wb[4*q+0] = qb[q].x; wb[4*q+1] = qb[q].y;
                wb[4*q+2] = qb[q].z; wb[4*q+3] = qb[q].w;
            }
        } else {
            #pragma unroll
            for (int j = 0; j < 28; ++j) {
                const int gx = gxb + j;
                const bool ok = rowok && ((unsigned)gx < (unsigned)IMG);
                wa[j] = ok ? ra[gx] : 0.f;
                wb[j] = ok ? rb[gx] : 0.f;
            }
        }

        // products-once scatter: 12 outputs x 11 taps x 4 planes
        float sa[12], sb[12], ss[12], sp[12];
        #pragma unroll
        for (int p = 0; p < 12; ++p)
        { sa[p]=0.f; sb[p]=0.f; ss[p]=0.f; sp[p]=0.f; }
        #pragma unroll
        for (int m = 0; m < 22; ++m) {
            const float a = wa[3 + m];
            const float b = wb[3 + m];
            const float s2v = a * a + b * b;     // A^2 + B^2 (conv is linear)
            const float ab  = a * b;
            #pragma unroll
            for (int p = 0; p < 12; ++p) {
                const int k = m - p;             // tap index (compile-time)
                if (k >= 0 && k <= 10) {
                    const float w = gw.g[k];
                    sa[p] += w * a;   sb[p] += w * b;
                    ss[p] += w * s2v; sp[p] += w * ab;
                }
            }
        }

        const int base = r * RSF;
        #pragma unroll
        for (int p = 0; p < 12; ++p) {
            *(float4*)&hbuf[base + (start + p) * 4] =
                make_float4(sa[p], sb[p], ss[p], sp[p]);
        }
    }
    __syncthreads();

    // ---------------- vertical pass + SSIM ----------------
    // 256 threads: column x = t&63, output rows yb..yb+7 (yb = (t>>6)*8).
    // All 18 float4 reads issued up front (q[] statically indexed).
    float lsum = 0.f;
    {
        const int x  = t & 63;
        const int yb = (t >> 6) << 3;

        float4 q[18];
        #pragma unroll
        for (int k = 0; k < 18; ++k)
            q[k] = *(const float4*)&hbuf[(yb + k) * RSF + x * 4];

        float m1[8], m2[8], es[8], ep[8];
        #pragma unroll
        for (int j = 0; j < 8; ++j)
        { m1[j]=0.f; m2[j]=0.f; es[j]=0.f; ep[j]=0.f; }

        #pragma unroll
        for (int k = 0; k < 18; ++k) {
            #pragma unroll
            for (int j = 0; j < 8; ++j) {
                const int kk = k - j;
                if (kk >= 0 && kk <= 10) {
                    const float w = gw.g[kk];
                    m1[j] += w * q[k].x; m2[j] += w * q[k].y;
                    es[j] += w * q[k].z; ep[j] += w * q[k].w;
                }
            }
        }

        #pragma unroll
        for (int j = 0; j < 8; ++j) {
            const float mu1 = m1[j], mu2 = m2[j];
            const float mu1s = mu1 * mu1, mu2s = mu2 * mu2, mu12 = mu1 * mu2;
            const float s12  = ep[j] - mu12;                 // sigma12
            const float ssum = es[j] - mu1s - mu2s;          // sigma1+sigma2
            const float num = (2.f * mu12 + C1F) * (2.f * s12 + C2F);
            const float den = (mu1s + mu2s + C1F) * (ssum + C2F);
            lsum += num * __builtin_amdgcn_rcpf(den);        // ~1ulp, in-slack
        }
    }

    // ---------------- reduction ----------------
    #pragma unroll
    for (int off = 32; off > 0; off >>= 1)
        lsum += __shfl_down(lsum, off, 64);

    __syncthreads();                  // LDS reads done; reuse hbuf for partials
    if ((t & 63) == 0) hbuf[t >> 6] = lsum;
    __syncthreads();
    if (t == 0) {
        const double bs = (double)hbuf[0] + (double)hbuf[1]
                        + (double)hbuf[2] + (double)hbuf[3];
        const int slot = blockIdx.x + (blockIdx.y << 3) + (blockIdx.z << 7);
        part[slot] = bs;              // private slot, no atomics
    }
}

extern "C" void kernel_launch(void* const* d_in, const int* in_sizes, int n_in,
                              void* d_out, int out_size, void* d_ws, size_t ws_size,
                              hipStream_t stream) {
    const float* A = (const float*)d_in[0];
    const float* B = (const float*)d_in[1];
    float* out   = (float*)d_out;
    double* part = (double*)d_ws;                // 6144 doubles = 48KB

    // Weights in f64, exactly the NumPy pipeline: exp(f64) -> sum(f64) ->
    // divide(f64) -> round to f32. Same every call (graph-capture safe).
    GW gw;
    {
        double e[11], s = 0.0;
        for (int i = 0; i < 11; ++i) {
            const double d = (double)(i - 5);
            e[i] = exp(-d * d / 4.5);
            s += e[i];
        }
        for (int i = 0; i < 11; ++i) gw.g[i] = (float)(e[i] / s);
    }

    dim3 grid(IMG / 64, IMG / 32, 48);           // (8, 16, 48) = 6144 blocks
    ssim_main<<<grid, dim3(256), 0, stream>>>(A, B, part, gw);
    ssim_finalize<<<dim3(1), dim3(256), 0, stream>>>(part, out);
}

// Round 9
// 151.906 us; speedup vs baseline: 1.0469x; 1.0167x over previous
//
#include <hip/hip_runtime.h>
#include <math.h>

// SSIM fused kernel for MI355X (gfx950), v9.
// A,B: [16,3,512,512] f32 -> scalar f32 mean(ssim_map).
// Separable 11-tap Gaussian, zero-padded SAME conv, 4 staged planes
// {hA, hB, h(A^2+B^2), h(AB)} (sigma1+sigma2 via linearity).
// v9 = v8 retiled 64x32 -> 32x32. VGPR=68 proved the kernel fits 7
// waves/SIMD; occupancy was purely LDS-limited (44KB x3). New LDS:
// 42 rows x 132 floats = 22,176B -> alloc 22,528 -> 7 blocks/CU = 28
// waves/CU (was 12). Compute halo unchanged (42/32 rows); only fetch
// halo grows (L2/L3-absorbed). Same weights/products/rcp as v8.

#define IMG 512
#define C1F 1.0e-4f
#define C2F 9.0e-4f

#define SR  42               // h-rows per tile (TY=32 + 10 halo)
#define RSF 132              // row stride in floats: 32 cols * 4 planes + 4 pad

#define NBLK 12288           // 16 * 16 * 48

struct GW { float g[11]; };

__global__ void ssim_finalize(const double* __restrict__ part, float* __restrict__ out) {
    const int t = threadIdx.x;           // 256 threads
    double v = 0.0;
    #pragma unroll
    for (int i = 0; i < NBLK / 256; ++i)     // 48 iters
        v += part[t + 256 * i];
    #pragma unroll
    for (int off = 32; off > 0; off >>= 1)
        v += __shfl_down(v, off, 64);
    __shared__ double w[4];
    if ((t & 63) == 0) w[t >> 6] = v;
    __syncthreads();
    if (t == 0)
        *out = (float)((w[0] + w[1] + w[2] + w[3]) / 12582912.0);  // 16*3*512^2
}

__global__ __launch_bounds__(256, 7)
void ssim_main(const float* __restrict__ A, const float* __restrict__ B,
               double* __restrict__ part, const GW gw)
{
    __shared__ float hbuf[SR * RSF];   // 5,544 floats = 22,176 B

    const int t  = threadIdx.x;
    const int x0 = blockIdx.x * 32;
    const int y0 = blockIdx.y * 32;
    const size_t pbase = (size_t)blockIdx.z * (size_t)(IMG * IMG);
    const float* __restrict__ pa = A + pbase;
    const float* __restrict__ pb = B + pbase;

    // ---------------- horizontal pass ----------------
    // 168 threads: r = t>>2 (0..41), s = t&3. Segment s covers 8 output cols
    // from start = 8s. Window cols [start-8, start+16): base 4-aligned for
    // all lanes -> 6 aligned float4 loads per image. Taps use window idx
    // m+3, m=0..17 (cols start-5 .. start+12).
    if (t < 168) {
        const int r = t >> 2;
        const int s = t & 3;
        const int start = s << 3;
        const int gy  = y0 - 5 + r;
        const int gxb = x0 + start - 8;          // = 0 mod 4 always
        const bool rowok = ((unsigned)gy < (unsigned)IMG);
        const float* __restrict__ ra = pa + (ptrdiff_t)gy * IMG;
        const float* __restrict__ rb = pb + (ptrdiff_t)gy * IMG;

        float wa[24], wb[24];
        if (rowok && gxb >= 0 && gxb + 24 <= IMG) {
            const float4* va = (const float4*)(ra + gxb);
            const float4* vb = (const float4*)(rb + gxb);
            float4 qa[6], qb[6];
            #pragma unroll
            for (int q = 0; q < 6; ++q) qa[q] = va[q];   // batched: one wait
            #pragma unroll
            for (int q = 0; q < 6; ++q) qb[q] = vb[q];
            #pragma unroll
            for (int q = 0; q < 6; ++q) {
                wa[4*q+0] = qa[q].x; wa[4*q+1] = qa[q].y;
                wa[4*q+2] = qa[q].z; wa[4*q+3] = qa[q].w;
                wb[4*q+0] = qb[q].x; wb[4*q+1] = qb[q].y;
                wb[4*q+2] = qb[q].z; wb[4*q+3] = qb[q].w;
            }
        } else {
            #pragma unroll
            for (int j = 0; j < 24; ++j) {
                const int gx = gxb + j;
                const bool ok = rowok && ((unsigned)gx < (unsigned)IMG);
                wa[j] = ok ? ra[gx] : 0.f;
                wb[j] = ok ? rb[gx] : 0.f;
            }
        }

        // products-once scatter: 8 outputs x 11 taps x 4 planes
        float sa[8], sb[8], ss[8], sp[8];
        #pragma unroll
        for (int p = 0; p < 8; ++p)
        { sa[p]=0.f; sb[p]=0.f; ss[p]=0.f; sp[p]=0.f; }
        #pragma unroll
        for (int m = 0; m < 18; ++m) {
            const float a = wa[3 + m];
            const float b = wb[3 + m];
            const float s2v = a * a + b * b;     // A^2 + B^2 (conv is linear)
            const float ab  = a * b;
            #pragma unroll
            for (int p = 0; p < 8; ++p) {
                const int k = m - p;             // tap index (compile-time)
                if (k >= 0 && k <= 10) {
                    const float w = gw.g[k];
                    sa[p] += w * a;   sb[p] += w * b;
                    ss[p] += w * s2v; sp[p] += w * ab;
                }
            }
        }

        const int base = r * RSF;
        #pragma unroll
        for (int p = 0; p < 8; ++p) {
            *(float4*)&hbuf[base + (start + p) * 4] =
                make_float4(sa[p], sb[p], ss[p], sp[p]);
        }
    }
    __syncthreads();

    // ---------------- vertical pass + SSIM ----------------
    // 256 threads: column x = t&31, output rows yb..yb+3 (yb = (t>>5)*4).
    // 14 float4 LDS reads staged before the FMAs.
    float lsum = 0.f;
    {
        const int x  = t & 31;
        const int yb = (t >> 5) << 2;

        float4 q[14];
        #pragma unroll
        for (int k = 0; k < 14; ++k)
            q[k] = *(const float4*)&hbuf[(yb + k) * RSF + x * 4];

        float m1[4], m2[4], es[4], ep[4];
        #pragma unroll
        for (int j = 0; j < 4; ++j)
        { m1[j]=0.f; m2[j]=0.f; es[j]=0.f; ep[j]=0.f; }

        #pragma unroll
        for (int k = 0; k < 14; ++k) {
            #pragma unroll
            for (int j = 0; j < 4; ++j) {
                const int kk = k - j;
                if (kk >= 0 && kk <= 10) {
                    const float w = gw.g[kk];
                    m1[j] += w * q[k].x; m2[j] += w * q[k].y;
                    es[j] += w * q[k].z; ep[j] += w * q[k].w;
                }
            }
        }

        #pragma unroll
        for (int j = 0; j < 4; ++j) {
            const float mu1 = m1[j], mu2 = m2[j];
            const float mu1s = mu1 * mu1, mu2s = mu2 * mu2, mu12 = mu1 * mu2;
            const float s12  = ep[j] - mu12;                 // sigma12
            const float ssum = es[j] - mu1s - mu2s;          // sigma1+sigma2
            const float num = (2.f * mu12 + C1F) * (2.f * s12 + C2F);
            const float den = (mu1s + mu2s + C1F) * (ssum + C2F);
            lsum += num * __builtin_amdgcn_rcpf(den);        // ~1ulp, in-slack
        }
    }

    // ---------------- reduction ----------------
    #pragma unroll
    for (int off = 32; off > 0; off >>= 1)
        lsum += __shfl_down(lsum, off, 64);

    __syncthreads();                  // LDS reads done; reuse hbuf for partials
    if ((t & 63) == 0) hbuf[t >> 6] = lsum;
    __syncthreads();
    if (t == 0) {
        const double bs = (double)hbuf[0] + (double)hbuf[1]
                        + (double)hbuf[2] + (double)hbuf[3];
        const int slot = blockIdx.x + (blockIdx.y << 4) + (blockIdx.z << 8);
        part[slot] = bs;              // private slot, no atomics
    }
}

extern "C" void kernel_launch(void* const* d_in, const int* in_sizes, int n_in,
                              void* d_out, int out_size, void* d_ws, size_t ws_size,
                              hipStream_t stream) {
    const float* A = (const float*)d_in[0];
    const float* B = (const float*)d_in[1];
    float* out   = (float*)d_out;
    double* part = (double*)d_ws;                // 12288 doubles = 96KB

    // Weights in f64, exactly the NumPy pipeline: exp(f64) -> sum(f64) ->
    // divide(f64) -> round to f32. Same every call (graph-capture safe).
    GW gw;
    {
        double e[11], s = 0.0;
        for (int i = 0; i < 11; ++i) {
            const double d = (double)(i - 5);
            e[i] = exp(-d * d / 4.5);
            s += e[i];
        }
        for (int i = 0; i < 11; ++i) gw.g[i] = (float)(e[i] / s);
    }

    dim3 grid(IMG / 32, IMG / 32, 48);           // (16, 16, 48) = 12288 blocks
    ssim_main<<<grid, dim3(256), 0, stream>>>(A, B, part, gw);
    ssim_finalize<<<dim3(1), dim3(256), 0, stream>>>(part, out);
}